// Round 3
// baseline (488.587 us; speedup 1.0000x reference)
//
#include <hip/hip_runtime.h>

// ---- problem constants ----
// B=2, T=2048, TREF=512, C=768, H=12, D=64, L=T+TREF=2560

typedef __bf16 bf16x8 __attribute__((ext_vector_type(8)));
typedef float floatx4 __attribute__((ext_vector_type(4)));
typedef uint uintx2 __attribute__((ext_vector_type(2)));

__device__ __forceinline__ ushort f2bf(float f) {
  uint u = __builtin_bit_cast(uint, f);
  return (ushort)((u + 0x7FFFu + ((u >> 16) & 1u)) >> 16);
}

__device__ __forceinline__ uint pack2bf(float lo, float hi) {
  ushort a = __builtin_bit_cast(ushort, (__bf16)lo);
  ushort b = __builtin_bit_cast(ushort, (__bf16)hi);
  return (uint)a | ((uint)b << 16);
}

__device__ __forceinline__ float fexp2(float x) {
#if __has_builtin(__builtin_amdgcn_exp2f)
  return __builtin_amdgcn_exp2f(x);
#else
  return exp2f(x);
#endif
}

// async global->LDS, 16B per lane; LDS dest = wave-uniform base + lane*16
__device__ __forceinline__ void gld16(ushort* lds, const ushort* g) {
  __builtin_amdgcn_global_load_lds(
      (const __attribute__((address_space(1))) unsigned int*)g,
      (__attribute__((address_space(3))) unsigned int*)lds, 16, 0, 0);
}

// ---------------- cast kernel: fp32 -> bf16 for x, ref_feat, 6 weights ----------------
__global__ __launch_bounds__(256) void cast_all(
    const float* __restrict__ x, const float* __restrict__ rf,
    const float* __restrict__ w0, const float* __restrict__ w1,
    const float* __restrict__ w2, const float* __restrict__ w3,
    const float* __restrict__ w4, const float* __restrict__ w5,
    ushort* __restrict__ dst) {
  size_t i4 = ((size_t)blockIdx.x * 256 + threadIdx.x) * 4;
  const float* src;
  size_t off;
  if (i4 < 3145728) { src = x; off = i4; }
  else if (i4 < 3932160) { src = rf; off = i4 - 3145728; }
  else {
    size_t r = i4 - 3932160;
    if (r < 589824) { src = w0; off = r; }
    else if (r < 2 * 589824) { src = w1; off = r - 589824; }
    else if (r < 3 * 589824) { src = w2; off = r - 2 * 589824; }
    else if (r < 4 * 589824) { src = w3; off = r - 3 * 589824; }
    else if (r < 5 * 589824) { src = w4; off = r - 4 * 589824; }
    else { src = w5; off = r - 5 * 589824; }
  }
  float4 v = *(const float4*)(src + off);
  ushort4 o;
  o.x = f2bf(v.x); o.y = f2bf(v.y); o.z = f2bf(v.z); o.w = f2bf(v.w);
  *(ushort4*)(dst + i4) = o;
}

// ---------------- mask bit-pack: mask[b][t][2048] int32 -> bits[b][t][32] u64 ----------------
__global__ __launch_bounds__(256) void pack_mask(
    const int* __restrict__ mask, unsigned long long* __restrict__ bits) {
  const int gid = blockIdx.x * 256 + threadIdx.x;  // [0, 131072)
  const int4* src = (const int4*)(mask + (size_t)gid * 64);
  unsigned long long v = 0;
#pragma unroll
  for (int j = 0; j < 16; ++j) {
    int4 m = src[j];
    unsigned long long nib = (m.x ? 1ull : 0ull) | (m.y ? 2ull : 0ull) |
                             (m.z ? 4ull : 0ull) | (m.w ? 8ull : 0ull);
    v |= nib << (j * 4);
  }
  bits[gid] = v;
}

// ---------------- shared GEMM core: 128x128 tile, K=768, gld16 double-buffered ----------------
__device__ __forceinline__ void gemm_core(
    const ushort* __restrict__ Ab, const ushort* __restrict__ Bb,
    ushort* As, ushort* Bs, int tid, int quad, int l16, int mw, int nw,
    floatx4 acc[4][4]) {
  const int w = tid >> 6;
  const int r0 = tid >> 2, kp = (tid & 3) * 8;
  const size_t ga0 = (size_t)r0 * 768 + kp;
  const size_t ga1 = ga0 + (size_t)64 * 768;
#define GEMM_ISSUE(kb, p)                                   \
  do {                                                      \
    const int k0_ = (kb) * 32;                              \
    gld16(&As[(p) * 4096 + w * 512], Ab + ga0 + k0_);       \
    gld16(&As[(p) * 4096 + w * 512 + 2048], Ab + ga1 + k0_);\
    gld16(&Bs[(p) * 4096 + w * 512], Bb + ga0 + k0_);       \
    gld16(&Bs[(p) * 4096 + w * 512 + 2048], Bb + ga1 + k0_);\
  } while (0)
  GEMM_ISSUE(0, 0);
#pragma unroll 1
  for (int kb = 0; kb < 24; ++kb) {
    __syncthreads();
    if (kb < 23) GEMM_ISSUE(kb + 1, (kb + 1) & 1);
    const int p = kb & 1;
    bf16x8 af[4], bfr[4];
#pragma unroll
    for (int mt = 0; mt < 4; ++mt)
      af[mt] = *(const bf16x8*)&As[p * 4096 + (mw + mt * 16 + l16) * 32 + quad * 8];
#pragma unroll
    for (int nt = 0; nt < 4; ++nt)
      bfr[nt] = *(const bf16x8*)&Bs[p * 4096 + (nw + nt * 16 + l16) * 32 + quad * 8];
#pragma unroll
    for (int mt = 0; mt < 4; ++mt)
#pragma unroll
      for (int nt = 0; nt < 4; ++nt)
        acc[mt][nt] = __builtin_amdgcn_mfma_f32_16x16x32_bf16(af[mt], bfr[nt], acc[mt][nt], 0, 0, 0);
  }
#undef GEMM_ISSUE
}

// ---------------- fused projection GEMMs ----------------
// Q path (REF==0, sec==0): output pre-scaled by 0.125*log2(e) (exp2-domain).
// V path (REF==0 sec==2; REF==1 sec==1): stored TRANSPOSED as [b][h][d][key]
// so the attention kernel can stage V^T exactly like K (no transpose needed).
template <int REF>
__global__ __launch_bounds__(256) void gemm_fused(
    const ushort* __restrict__ A, const ushort* __restrict__ W,
    const float* __restrict__ bA, const float* __restrict__ bB,
    const float* __restrict__ bC,
    ushort* __restrict__ oA, ushort* __restrict__ oB, ushort* __restrict__ oC) {
  const int bm = blockIdx.x, bn = blockIdx.y;
  const int tid = threadIdx.x;
  const int w = tid >> 6, lane = tid & 63, quad = lane >> 4, l16 = lane & 15;
  const int mw = (w >> 1) * 64, nw = (w & 1) * 64;

  __shared__ __align__(16) ushort As[2 * 4096];
  __shared__ __align__(16) ushort Bs[2 * 4096];

  floatx4 acc[4][4];
#pragma unroll
  for (int mt = 0; mt < 4; ++mt)
#pragma unroll
    for (int nt = 0; nt < 4; ++nt) acc[mt][nt] = (floatx4){0.f, 0.f, 0.f, 0.f};

  gemm_core(A + (size_t)bm * 128 * 768, W + (size_t)bn * 128 * 768,
            As, Bs, tid, quad, l16, mw, nw, acc);

  const int sec = bn / 6;
  const float* bp = sec == 0 ? bA : sec == 1 ? bB : bC;
  ushort* op = sec == 0 ? oA : sec == 1 ? oB : oC;
  const bool qlay = (REF == 0 && sec == 0);
  const bool vlay = (REF == 0) ? (sec == 2) : (sec == 1);
  const float scl = qlay ? 0.18033688011112042f : 1.0f;  // 0.125 * log2(e)
#pragma unroll
  for (int nt = 0; nt < 4; ++nt) {
    const int nloc = (bn - sec * 6) * 128 + nw + nt * 16 + l16;
    const float bv = bp[nloc];
    const int hh = nloc >> 6, dd = nloc & 63;
    if (vlay) {
      // V^T store: [b][h][d=64][key=2560]; 4 consecutive keys per (mt)
#pragma unroll
      for (int mt = 0; mt < 4; ++mt) {
        const int m0 = bm * 128 + mw + mt * 16 + quad * 4;
        int bb, t0;
        if (REF == 0) { bb = m0 >> 11; t0 = m0 & 2047; }
        else { bb = m0 >> 9; t0 = (m0 & 511) + 2048; }
        ushort4 o;
        o.x = f2bf(acc[mt][nt][0] + bv);
        o.y = f2bf(acc[mt][nt][1] + bv);
        o.z = f2bf(acc[mt][nt][2] + bv);
        o.w = f2bf(acc[mt][nt][3] + bv);
        *(ushort4*)&op[((size_t)(bb * 12 + hh) * 64 + dd) * 2560 + t0] = o;
      }
    } else {
#pragma unroll
      for (int mt = 0; mt < 4; ++mt)
#pragma unroll
        for (int i = 0; i < 4; ++i) {
          const int m = bm * 128 + mw + mt * 16 + quad * 4 + i;
          int bb, tt;
          if (REF == 0) { bb = m >> 11; tt = m & 2047; }
          else { bb = m >> 9; tt = (m & 511) + 2048; }
          const size_t idx = qlay ? (((size_t)(bb * 12 + hh) * 2048 + tt) * 64 + dd)
                                  : (((size_t)(bb * 12 + hh) * 2560 + tt) * 64 + dd);
          op[idx] = f2bf((acc[mt][nt][i] + bv) * scl);
        }
    }
  }
}

// ---------------- output projection: fp32 out ----------------
__global__ __launch_bounds__(256) void gemm_out(
    const ushort* __restrict__ A, const ushort* __restrict__ W,
    const float* __restrict__ bias, float* __restrict__ out) {
  const int bm = blockIdx.x, bn = blockIdx.y;
  const int tid = threadIdx.x;
  const int w = tid >> 6, lane = tid & 63, quad = lane >> 4, l16 = lane & 15;
  const int mw = (w >> 1) * 64, nw = (w & 1) * 64;

  __shared__ __align__(16) ushort As[2 * 4096];
  __shared__ __align__(16) ushort Bs[2 * 4096];

  floatx4 acc[4][4];
#pragma unroll
  for (int mt = 0; mt < 4; ++mt)
#pragma unroll
    for (int nt = 0; nt < 4; ++nt) acc[mt][nt] = (floatx4){0.f, 0.f, 0.f, 0.f};

  gemm_core(A + (size_t)bm * 128 * 768, W + (size_t)bn * 128 * 768,
            As, Bs, tid, quad, l16, mw, nw, acc);

#pragma unroll
  for (int nt = 0; nt < 4; ++nt) {
    const int n = bn * 128 + nw + nt * 16 + l16;
    const float bv = bias[n];
#pragma unroll
    for (int mt = 0; mt < 4; ++mt)
#pragma unroll
      for (int i = 0; i < 4; ++i) {
        const int m = bm * 128 + mw + mt * 16 + quad * 4 + i;
        out[(size_t)m * 768 + n] = acc[mt][nt][i] + bv;
      }
  }
}

// ---------------- flash attention v6 ----------------
// grid (B, T/64, H), 256 threads = 4 waves; wave w owns q-rows [w*16,w*16+16).
// S^T = K.Q^T (lane owns q-column l16), exp2-domain (Q pre-scaled in GEMM).
// K AND V^T both staged via gld16 double-buffers with XOR-swizzled SOURCE
// (LDS dest linear) — V is already transposed in global ([b][h][d][key]),
// so its staging/read path is structurally identical to K's.
// Q fragments load directly from global (no LDS staging).
// rel_pos loads fp32 directly in consumption layout, folded via fma(log2e).
// P^T staged per-wave in interleaved [chunk][row][8key] LDS.
// Softmax: online, exp2-domain, defer-max (T13).
__global__ __launch_bounds__(256, 3) void attn(
    const ushort* __restrict__ qb, const ushort* __restrict__ kb,
    const ushort* __restrict__ vb, const unsigned long long* __restrict__ bits,
    const float* __restrict__ relp, ushort* __restrict__ yb) {
  const int b = blockIdx.x, qt = blockIdx.y, h = blockIdx.z;
  const int tid = threadIdx.x;
  const int w = tid >> 6, lane = tid & 63, quad = lane >> 4, l16 = lane & 15;

  __shared__ __align__(16) ushort Kl[2][4096];      // [key][d]  XOR-chunk swizzled
  __shared__ __align__(16) ushort Vtl[2][4096];     // [d][key]  XOR-chunk swizzled
  __shared__ __align__(16) ushort Ps[4][8][16][8];  // [wave][key-chunk][q-row][8key]

  const ushort* qsrc = qb + ((size_t)(b * 12 + h) * 2048 + qt * 64) * 64;
  const ushort* ksrc = kb + (size_t)(b * 12 + h) * 2560 * 64;
  const ushort* vtsrc = vb + (size_t)(b * 12 + h) * 64 * 2560;  // [d][key]
  const int qrow = qt * 64 + w * 16 + l16;
  const unsigned long long* brow = bits + ((size_t)b * 2048 + qrow) * 32;
  const float* rrow = relp + ((size_t)h * 2048 + qrow) * 2048;

  // staging source swizzle (XOR realized on the global address)
  const int krow = lane >> 3;            // row within the 8-row gld16 group
  const int kchunk = (lane & 7) ^ krow;  // XOR-swizzled source chunk

  // ---- issue K(0), V^T(0) ----
#pragma unroll
  for (int c = 0; c < 2; ++c) {
    const int rb = w * 16 + c * 8;
    gld16(&Kl[0][rb * 64], ksrc + (rb + krow) * 64 + kchunk * 8);
    gld16(&Vtl[0][rb * 64], vtsrc + (size_t)(rb + krow) * 2560 + kchunk * 8);
  }

  // ---- Q fragments direct from global (persist in regs) ----
  bf16x8 bQ[2];
  bQ[0] = *(const bf16x8*)(qsrc + (w * 16 + l16) * 64 + quad * 8);
  bQ[1] = *(const bf16x8*)(qsrc + (w * 16 + l16) * 64 + 32 + quad * 8);

  // ---- prefetch rel(0), bits(0) in consumption layout ----
  float4 rd[4];
#pragma unroll
  for (int mt = 0; mt < 4; ++mt)
    rd[mt] = *(const float4*)(rrow + mt * 16 + quad * 4);
  unsigned long long bnext = brow[0];

  floatx4 acc[4];
#pragma unroll
  for (int mt = 0; mt < 4; ++mt) acc[mt] = (floatx4){0.f, 0.f, 0.f, 0.f};
  float m_run = -__builtin_inff(), l_run = 0.f;

#pragma unroll 1
  for (int it = 0; it < 40; ++it) {
    const int p = it & 1;
    const bool self = it < 32;
    const unsigned long long bcur = bnext;
    __syncthreads();  // drains gld16(it): K/V^T(it) visible; all waves past it-1 reads

    // ---- prefetch K/V^T(it+1) into other parity ----
    const int itn = it + 1;
    if (itn < 40) {
      const int pn = itn & 1;
#pragma unroll
      for (int c = 0; c < 2; ++c) {
        const int rb = w * 16 + c * 8;
        gld16(&Kl[pn][rb * 64],
              ksrc + (size_t)itn * 4096 + (rb + krow) * 64 + kchunk * 8);
        gld16(&Vtl[pn][rb * 64],
              vtsrc + (size_t)(rb + krow) * 2560 + itn * 64 + kchunk * 8);
      }
    }

    // ---- S^T = K.Q^T (already exp2-domain via Q pre-scale) ----
    floatx4 st[4];
#pragma unroll
    for (int mt = 0; mt < 4; ++mt) st[mt] = (floatx4){0.f, 0.f, 0.f, 0.f};
#pragma unroll
    for (int kk = 0; kk < 2; ++kk)
#pragma unroll
      for (int mt = 0; mt < 4; ++mt) {
        const bf16x8 aK = *(const bf16x8*)
            &Kl[p][(mt * 16 + l16) * 64 + (((kk * 4 + quad) ^ (l16 & 7)) * 8)];
        st[mt] = __builtin_amdgcn_mfma_f32_16x16x32_bf16(aK, bQ[kk], st[mt], 0, 0, 0);
      }

    // ---- rel (fp32, direct) + mask ----
    if (self) {
#pragma unroll
      for (int mt = 0; mt < 4; ++mt) {
        const float rr[4] = {rd[mt].x, rd[mt].y, rd[mt].z, rd[mt].w};
        const uint ni = (uint)(bcur >> (mt * 16 + quad * 4)) & 0xFu;
#pragma unroll
        for (int i = 0; i < 4; ++i) {
          const float sv = fmaf(rr[i], 1.4426950408889634f, st[mt][i]);
          st[mt][i] = (ni & (1u << i)) ? -__builtin_inff() : sv;
        }
      }
    }
    // ---- prefetch rel/bits(it+1) (after rd consumed) ----
    if (itn < 32) {
#pragma unroll
      for (int mt = 0; mt < 4; ++mt)
        rd[mt] = *(const float4*)(rrow + itn * 64 + mt * 16 + quad * 4);
      bnext = brow[itn];
    }

    // ---- online softmax (exp2-domain, per q-column l16, defer-max) ----
    float tm = fmaxf(fmaxf(st[0][0], st[0][1]), fmaxf(st[0][2], st[0][3]));
#pragma unroll
    for (int mt = 1; mt < 4; ++mt)
      tm = fmaxf(tm, fmaxf(fmaxf(st[mt][0], st[mt][1]), fmaxf(st[mt][2], st[mt][3])));
    tm = fmaxf(tm, __shfl_xor(tm, 16));
    tm = fmaxf(tm, __shfl_xor(tm, 32));
    float mref;
    if (__all(tm - m_run <= 8.f)) {  // NaN/-inf-safe: -inf m_run never skips
      mref = m_run;
    } else {
      const float mnew = fmaxf(m_run, tm);
      mref = (mnew == -__builtin_inff()) ? 0.f : mnew;
      const float alpha =
          (m_run == -__builtin_inff()) ? 0.f : fexp2(m_run - mnew);
      m_run = mnew;
      l_run *= alpha;
#pragma unroll
      for (int mt = 0; mt < 4; ++mt) acc[mt] *= alpha;
    }
    float rs = 0.f;
#pragma unroll
    for (int mt = 0; mt < 4; ++mt)
#pragma unroll
      for (int i = 0; i < 4; ++i) {
        const float pv = fexp2(st[mt][i] - mref);
        st[mt][i] = pv;
        rs += pv;
      }
    rs += __shfl_xor(rs, 16);
    rs += __shfl_xor(rs, 32);
    l_run += rs;

    // ---- P^T pack -> own wave's Ps (native cvt -> v_cvt_pk_bf16_f32) ----
    {
      ushort* pwb = &Ps[w][quad >> 1][l16][(quad & 1) * 4];
#pragma unroll
      for (int mt = 0; mt < 4; ++mt) {
        uintx2 pkv;
        pkv.x = pack2bf(st[mt][0], st[mt][1]);
        pkv.y = pack2bf(st[mt][2], st[mt][3]);
        *(uintx2*)(pwb + mt * 256) = pkv;
      }
    }

    // ---- O^T += V^T . P^T  (V^T fragments: same form as K reads) ----
    const bf16x8 bP0 = *(const bf16x8*)&Ps[w][quad][l16][0];
    const bf16x8 bP1 = *(const bf16x8*)&Ps[w][4 + quad][l16][0];
#pragma unroll
    for (int kk = 0; kk < 2; ++kk) {
      const bf16x8 bPk = kk ? bP1 : bP0;
#pragma unroll
      for (int mt = 0; mt < 4; ++mt) {
        const bf16x8 aV = *(const bf16x8*)
            &Vtl[p][(mt * 16 + l16) * 64 + (((kk * 4 + quad) ^ (l16 & 7)) * 8)];
        acc[mt] = __builtin_amdgcn_mfma_f32_16x16x32_bf16(aV, bPk, acc[mt], 0, 0, 0);
      }
    }
  }

  // ---- epilogue: y[b][t][h*64+d] bf16 ----
  const float inv = 1.f / l_run;
  ushort* yrow = yb + ((size_t)b * 2048 + qt * 64 + w * 16 + l16) * 768 + h * 64;
#pragma unroll
  for (int mt = 0; mt < 4; ++mt)
#pragma unroll
    for (int i = 0; i < 4; ++i)
      yrow[mt * 16 + quad * 4 + i] = f2bf(acc[mt][i] * inv);
}

// ---------------- launch ----------------
extern "C" void kernel_launch(void* const* d_in, const int* in_sizes, int n_in,
                              void* d_out, int out_size, void* d_ws, size_t ws_size,
                              hipStream_t stream) {
  const float* x = (const float*)d_in[0];
  const int* mask = (const int*)d_in[1];
  const float* relp = (const float*)d_in[2];
  const float* ref = (const float*)d_in[3];
  const float* Wq = (const float*)d_in[4];
  const float* bq = (const float*)d_in[5];
  const float* Wk = (const float*)d_in[6];
  const float* bk = (const float*)d_in[7];
  const float* Wv = (const float*)d_in[8];
  const float* bv = (const float*)d_in[9];
  const float* Wrk = (const float*)d_in[10];
  const float* brk = (const float*)d_in[11];
  const float* Wrv = (const float*)d_in[12];
  const float* brv = (const float*)d_in[13];
  const float* Wo = (const float*)d_in[14];
  const float* bo = (const float*)d_in[15];

  ushort* xb = (ushort*)d_ws;                 // 3,145,728
  ushort* refb = xb + 3145728;                // 786,432
  ushort* wb = refb + 786432;                 // 6 * 589,824  (q,k,v,rk,rv,o)
  ushort* qbuf = wb + 6 * 589824;             // 3,145,728   [b][h][t][d]
  ushort* kbuf = qbuf + 3145728;              // 3,932,160   [b][h][key][d], L=2560
  ushort* vbuf = kbuf + 3932160;              // 3,932,160   [b][h][d][key]  (V^T!)
  ushort* ybuf = vbuf + 3932160;              // 3,145,728   [b][t][c]
  unsigned long long* bitsbuf = (unsigned long long*)(ybuf + 3145728);  // 131072 u64

  cast_all<<<7296, 256, 0, stream>>>(x, ref, Wq, Wk, Wv, Wrk, Wrv, Wo, xb);
  pack_mask<<<512, 256, 0, stream>>>(mask, bitsbuf);

  gemm_fused<0><<<dim3(32, 18), 256, 0, stream>>>(
      xb, wb, bq, bk, bv, qbuf, kbuf, vbuf);
  gemm_fused<1><<<dim3(8, 12), 256, 0, stream>>>(
      refb, wb + (size_t)3 * 589824, brk, brv, nullptr, kbuf, vbuf, nullptr);

  attn<<<dim3(2, 32, 12), 256, 0, stream>>>(qbuf, kbuf, vbuf, bitsbuf, relp, ybuf);

  gemm_out<<<dim3(32, 6), 256, 0, stream>>>(
      ybuf, wb + (size_t)5 * 589824, bo, (float*)d_out);
}